// Round 5
// baseline (30.760 us; speedup 1.0000x reference)
//
#include <hip/hip_runtime.h>

typedef __attribute__((ext_vector_type(8))) short bf16x8;
typedef __attribute__((ext_vector_type(4))) float f32x4;
typedef __attribute__((ext_vector_type(2))) float f32x2;

// Native cast -> v_cvt_pk_bf16_f32 on gfx950 (RNE).
__device__ __forceinline__ short f2bf(float x) {
    union { __bf16 h; short s; } u;
    u.h = (__bf16)x;
    return u.s;
}

// Fused skinny GEMMs. 256 blocks x 512 threads (8 waves).
//   blocks 0..127  : seq tile, rows m0=bid*32      (m=b*S+s, k=h; A rows contiguous)
//   blocks 128..255: hid tile, rows m0=(bid-128)*32 (m=b*H+h, k=s; A strided 4KB)
// 32-row tiles: hid blocks consume full 128B cache lines (16 h x 4B = 64B was 2x overfetch).
// Wave wv: subtile sub=wv&1 (16 rows), K-slice kslice=wv>>1 (256 k). LDS-reduce 4
// K-partials per subtile; epilogue folds cp_weight into the seq embeddings.
// MFMA k-slot mapping kg(g,j)=8g+j identical for A and B -> k-permutation invariant.
__global__ __launch_bounds__(512) void gemm_fused(
    const float* __restrict__ hs, const float* __restrict__ seqW,
    const float* __restrict__ hidW, const float* __restrict__ cpw,
    float* __restrict__ E /* [2][4096][32] */)
{
    __shared__ float red[8][16][32];

    const int bid = blockIdx.x;
    const bool hid = bid >= 128;
    const int mt  = hid ? bid - 128 : bid;
    const int tid = threadIdx.x;
    const int wv  = tid >> 6;
    const int sub = wv & 1;
    const int kslice = wv >> 1;
    const int l   = tid & 63;
    const int l15 = l & 15;
    const int g   = l >> 4;
    const int m0  = mt * 32;
    const int mrow = m0 + sub * 16 + l15;

    const float* __restrict__ W = hid ? hidW : seqW;
    size_t arow;
    if (hid) arow = ((size_t)(mrow >> 10) << 20) + (size_t)(mrow & 1023);
    else     arow = (size_t)mrow << 10;

    f32x4 acc0 = {0.f,0.f,0.f,0.f}, acc1 = {0.f,0.f,0.f,0.f};
    const int kbase = kslice * 256;

    for (int ks = 0; ks < 8; ++ks) {
        const int kb = kbase + ks * 32 + g * 8;
        bf16x8 af, bf0, bf1;
        if (hid) {
            const float* pa = hs + arow + (size_t)kb * 1024;
            float a[8];
            #pragma unroll
            for (int j = 0; j < 8; ++j) a[j] = pa[(size_t)j * 1024];
            #pragma unroll
            for (int j = 0; j < 8; ++j) af[j] = f2bf(a[j]);
        } else {
            const f32x4* pa = (const f32x4*)(hs + arow + kb);
            f32x4 a0 = pa[0], a1 = pa[1];
            af[0]=f2bf(a0.x); af[1]=f2bf(a0.y); af[2]=f2bf(a0.z); af[3]=f2bf(a0.w);
            af[4]=f2bf(a1.x); af[5]=f2bf(a1.y); af[6]=f2bf(a1.z); af[7]=f2bf(a1.w);
        }
        {
            const f32x4* pb = (const f32x4*)(W + (size_t)l15 * 1024 + kb);
            f32x4 b0 = pb[0], b1 = pb[1];
            bf0[0]=f2bf(b0.x); bf0[1]=f2bf(b0.y); bf0[2]=f2bf(b0.z); bf0[3]=f2bf(b0.w);
            bf0[4]=f2bf(b1.x); bf0[5]=f2bf(b1.y); bf0[6]=f2bf(b1.z); bf0[7]=f2bf(b1.w);
        }
        {
            const f32x4* pb = (const f32x4*)(W + (size_t)(l15 + 16) * 1024 + kb);
            f32x4 b0 = pb[0], b1 = pb[1];
            bf1[0]=f2bf(b0.x); bf1[1]=f2bf(b0.y); bf1[2]=f2bf(b0.z); bf1[3]=f2bf(b0.w);
            bf1[4]=f2bf(b1.x); bf1[5]=f2bf(b1.y); bf1[6]=f2bf(b1.z); bf1[7]=f2bf(b1.w);
        }
        acc0 = __builtin_amdgcn_mfma_f32_16x16x32_bf16(af, bf0, acc0, 0, 0, 0);
        acc1 = __builtin_amdgcn_mfma_f32_16x16x32_bf16(af, bf1, acc1, 0, 0, 0);
    }

    // C/D layout (m89-verified): col = lane&15, row = (lane>>4)*4 + reg
    #pragma unroll
    for (int r = 0; r < 4; ++r) {
        red[wv][4 * g + r][l15]      = acc0[r];
        red[wv][4 * g + r][l15 + 16] = acc1[r];
    }
    __syncthreads();

    // Sum the 4 K-slice partials of each subtile; fold cp_weight into seq half.
    // Output index o in [0,1024): subtile = o>>9, within-subtile idx = o&511.
    const int o    = tid * 2;
    const int subo = o >> 9;
    const int idx  = o & 511;
    const float* rf = &red[0][0][0];
    f32x2 v;
    v.x = rf[subo * 512 + idx]        + rf[(subo + 2) * 512 + idx]
        + rf[(subo + 4) * 512 + idx]  + rf[(subo + 6) * 512 + idx];
    v.y = rf[subo * 512 + idx + 1]       + rf[(subo + 2) * 512 + idx + 1]
        + rf[(subo + 4) * 512 + idx + 1] + rf[(subo + 6) * 512 + idx + 1];
    if (!hid) {
        f32x2 w = *(const f32x2*)(cpw + (o & 31));
        v.x *= w.x; v.y *= w.y;
    }
    float* Eo = E + (hid ? (size_t)4096 * 32 : 0) + (size_t)m0 * 32 + o;
    *(f32x2*)Eo = v;
}

// out[b][s][h] = sum_r SeqE[b*1024+s][r] * HidE[b*1024+h][r]   (cpw pre-folded)
// No LDS: each lane keeps its own HidE row (128B = one cache line) in 32 VGPRs;
// SeqE rows are wave-uniform -> s_load + FMA-with-SGPR-operand.
// Block: 256 thr = 4 waves; tile = 32 s x 64 h.
__global__ __launch_bounds__(256) void k3(const float* __restrict__ SeqE,
                                          const float* __restrict__ HidE,
                                          float* __restrict__ out)
{
    const int tid = threadIdx.x;
    const int b  = blockIdx.z;
    const int s0 = blockIdx.x * 32;
    const int h0 = blockIdx.y * 64;
    const int hx = tid & 63;
    const int sg = __builtin_amdgcn_readfirstlane(tid >> 6);

    const f32x4* hrow = (const f32x4*)(HidE + ((size_t)(b * 1024 + h0 + hx)) * 32);
    f32x4 hv[8];
    #pragma unroll
    for (int i = 0; i < 8; ++i) hv[i] = hrow[i];

    #pragma unroll
    for (int si = 0; si < 8; ++si) {
        const int s = s0 + sg * 8 + si;
        const f32x4* wrow = (const f32x4*)(SeqE + ((size_t)(b * 1024 + s)) * 32); // uniform
        float acc = 0.f;
        #pragma unroll
        for (int r4 = 0; r4 < 8; ++r4) {
            f32x4 w = wrow[r4];
            acc += w.x * hv[r4].x + w.y * hv[r4].y + w.z * hv[r4].z + w.w * hv[r4].w;
        }
        out[((size_t)(b * 1024 + s)) * 1024 + h0 + hx] = acc;
    }
}

extern "C" void kernel_launch(void* const* d_in, const int* in_sizes, int n_in,
                              void* d_out, int out_size, void* d_ws, size_t ws_size,
                              hipStream_t stream) {
    const float* hs   = (const float*)d_in[0];
    // d_in[1] = all_indices: identically (n/H, n%H) -> computed implicitly
    const float* seqW = (const float*)d_in[2];
    const float* hidW = (const float*)d_in[3];
    const float* cpw  = (const float*)d_in[4];
    float* out = (float*)d_out;

    float* E = (float*)d_ws;              // [2][4096][32] fp32, 1 MB

    gemm_fused<<<256, 512, 0, stream>>>(hs, seqW, hidW, cpw, E);
    dim3 grid3(32, 16, 4);
    k3<<<grid3, 256, 0, stream>>>(E, E + (size_t)4096 * 32, out);
}

// Round 6
// 27.716 us; speedup vs baseline: 1.1098x; 1.1098x over previous
//
#include <hip/hip_runtime.h>

typedef __attribute__((ext_vector_type(8))) short bf16x8;
typedef __attribute__((ext_vector_type(4))) float f32x4;
typedef __attribute__((ext_vector_type(2))) float f32x2;

// Native cast -> v_cvt_pk_bf16_f32 on gfx950 (RNE).
__device__ __forceinline__ short f2bf(float x) {
    union { __bf16 h; short s; } u;
    u.h = (__bf16)x;
    return u.s;
}

// K1: fused skinny GEMMs, 512 blocks x 256 thr.
//  bid<256 (seq): R4-proven path. 16-row tile, 4 waves K-split-256, LDS reduce,
//                 writes FINAL seqE. A rows contiguous -> full-line direct loads.
//  bid>=256 (hid): NEW coalesced path. hidE[b,h,r]=sum_s hs[b,s,h]*hidW[r,s].
//    Block = (b, 64-h tile, s-chunk of 256). 4 stages: stage hs[b,s0:s0+64,h0:h0+64]
//    into LDS tile[64][68] via full-line coalesced loads (each 256B row = 2 lines),
//    then each wave (= one 16-h subtile, both 16-r n-tiles) reads A-fragments down
//    LDS columns (k=s) and MFMAs. Writes fp32 partial P[chunk].
//    Pad 68: A-read bank = (s*68+h)&31 -> (s*4+h)&31, 4 g-groups alias -> 4-way max.
// MFMA k-slot mapping kg(g,j)=8g+j identical for A and B -> k-permutation invariant.
__global__ __launch_bounds__(256) void gemm_fused(
    const float* __restrict__ hs, const float* __restrict__ seqW,
    const float* __restrict__ hidW, float* __restrict__ E /* [2][4096][32] */,
    float* __restrict__ P /* [4][4096][32] hid partials */)
{
    __shared__ float lds[64 * 68];   // hid tile[64][68]=17408B; seq red uses first 8KB

    const int bid = blockIdx.x;
    const int tid = threadIdx.x;
    const int wv  = tid >> 6;
    const int l   = tid & 63;
    const int l15 = l & 15;
    const int g   = l >> 4;

    if (bid < 256) {
        // ---------------- seq path (verbatim R4 structure) ----------------
        const int m0 = bid * 16;
        const size_t arow = (size_t)(m0 + l15) << 10;
        f32x4 acc0 = {0.f,0.f,0.f,0.f}, acc1 = {0.f,0.f,0.f,0.f};
        const int kbase = wv * 256;

        for (int ks = 0; ks < 8; ++ks) {
            const int kb = kbase + ks * 32 + g * 8;
            bf16x8 af, bf0, bf1;
            {
                const f32x4* pa = (const f32x4*)(hs + arow + kb);
                f32x4 a0 = pa[0], a1 = pa[1];
                af[0]=f2bf(a0.x); af[1]=f2bf(a0.y); af[2]=f2bf(a0.z); af[3]=f2bf(a0.w);
                af[4]=f2bf(a1.x); af[5]=f2bf(a1.y); af[6]=f2bf(a1.z); af[7]=f2bf(a1.w);
            }
            {
                const f32x4* pb = (const f32x4*)(seqW + (size_t)l15 * 1024 + kb);
                f32x4 b0 = pb[0], b1 = pb[1];
                bf0[0]=f2bf(b0.x); bf0[1]=f2bf(b0.y); bf0[2]=f2bf(b0.z); bf0[3]=f2bf(b0.w);
                bf0[4]=f2bf(b1.x); bf0[5]=f2bf(b1.y); bf0[6]=f2bf(b1.z); bf0[7]=f2bf(b1.w);
            }
            {
                const f32x4* pb = (const f32x4*)(seqW + (size_t)(l15 + 16) * 1024 + kb);
                f32x4 b0 = pb[0], b1 = pb[1];
                bf1[0]=f2bf(b0.x); bf1[1]=f2bf(b0.y); bf1[2]=f2bf(b0.z); bf1[3]=f2bf(b0.w);
                bf1[4]=f2bf(b1.x); bf1[5]=f2bf(b1.y); bf1[6]=f2bf(b1.z); bf1[7]=f2bf(b1.w);
            }
            acc0 = __builtin_amdgcn_mfma_f32_16x16x32_bf16(af, bf0, acc0, 0, 0, 0);
            acc1 = __builtin_amdgcn_mfma_f32_16x16x32_bf16(af, bf1, acc1, 0, 0, 0);
        }
        // C/D layout (m89): col = lane&15, row = g*4 + reg. red[wv][16][32] in lds.
        #pragma unroll
        for (int r = 0; r < 4; ++r) {
            lds[wv * 512 + (4 * g + r) * 32 + l15]      = acc0[r];
            lds[wv * 512 + (4 * g + r) * 32 + l15 + 16] = acc1[r];
        }
        __syncthreads();
        const int o = tid * 2;
        f32x2 v;
        v.x = lds[o]     + lds[512 + o]     + lds[1024 + o]     + lds[1536 + o];
        v.y = lds[o + 1] + lds[512 + o + 1] + lds[1024 + o + 1] + lds[1536 + o + 1];
        *(f32x2*)(E + (size_t)m0 * 32 + o) = v;
    } else {
        // ---------------- hid path (coalesced LDS transpose) ----------------
        const int hb = bid - 256;       // 0..255
        const int c  = hb & 3;          // s-chunk (256 s each)
        const int t  = hb >> 2;         // 0..63
        const int b  = t >> 4;          // batch
        const int h0 = (t & 15) * 64;   // h-tile base
        const size_t hsb = (size_t)b << 20;

        f32x4 acc0 = {0.f,0.f,0.f,0.f}, acc1 = {0.f,0.f,0.f,0.f};

        for (int st = 0; st < 4; ++st) {
            const int s0 = c * 256 + st * 64;
            __syncthreads();
            // stage 64 s-rows x 64 h (16 KB): 4 f32x4 per thread, full-line coalesced
            #pragma unroll
            for (int k = 0; k < 4; ++k) {
                const int flat = tid + k * 256;
                const int row  = flat >> 4;
                const int c4   = (flat & 15) * 4;
                f32x4 vv = *(const f32x4*)(hs + hsb + (size_t)(s0 + row) * 1024 + h0 + c4);
                *(f32x4*)&lds[row * 68 + c4] = vv;
            }
            __syncthreads();

            #pragma unroll
            for (int kbl = 0; kbl < 64; kbl += 32) {
                bf16x8 af, bf0, bf1;
                #pragma unroll
                for (int j = 0; j < 8; ++j)
                    af[j] = f2bf(lds[(kbl + g * 8 + j) * 68 + wv * 16 + l15]);
                const int kg = c * 256 + st * 64 + kbl + g * 8;
                {
                    const f32x4* pb = (const f32x4*)(hidW + (size_t)l15 * 1024 + kg);
                    f32x4 b0 = pb[0], b1 = pb[1];
                    bf0[0]=f2bf(b0.x); bf0[1]=f2bf(b0.y); bf0[2]=f2bf(b0.z); bf0[3]=f2bf(b0.w);
                    bf0[4]=f2bf(b1.x); bf0[5]=f2bf(b1.y); bf0[6]=f2bf(b1.z); bf0[7]=f2bf(b1.w);
                }
                {
                    const f32x4* pb = (const f32x4*)(hidW + (size_t)(l15 + 16) * 1024 + kg);
                    f32x4 b0 = pb[0], b1 = pb[1];
                    bf1[0]=f2bf(b0.x); bf1[1]=f2bf(b0.y); bf1[2]=f2bf(b0.z); bf1[3]=f2bf(b0.w);
                    bf1[4]=f2bf(b1.x); bf1[5]=f2bf(b1.y); bf1[6]=f2bf(b1.z); bf1[7]=f2bf(b1.w);
                }
                acc0 = __builtin_amdgcn_mfma_f32_16x16x32_bf16(af, bf0, acc0, 0, 0, 0);
                acc1 = __builtin_amdgcn_mfma_f32_16x16x32_bf16(af, bf1, acc1, 0, 0, 0);
            }
        }
        // C/D layout: col=l15, row=4g+r. Output row = h (within wave's 16-h subtile).
        float* Pc = P + (size_t)c * 131072;
        #pragma unroll
        for (int r = 0; r < 4; ++r) {
            const int hrow = b * 1024 + h0 + wv * 16 + 4 * g + r;
            Pc[(size_t)hrow * 32 + l15]      = acc0[r];
            Pc[(size_t)hrow * 32 + 16 + l15] = acc1[r];
        }
    }
}

// K2: hidE = sum of 4 s-chunk partials. 128 blocks x 256 thr, 1 f32x4 each.
__global__ __launch_bounds__(256) void kreduce(const float* __restrict__ P,
                                               float* __restrict__ Ehid)
{
    const int idx = blockIdx.x * 256 + threadIdx.x;        // 0..32767 f4-units
    const f32x4* P4 = (const f32x4*)P;
    f32x4 v = P4[idx] + P4[idx + 32768] + P4[idx + 65536] + P4[idx + 98304];
    ((f32x4*)Ehid)[idx] = v;
}

// K3: verbatim R4. out[b][s][h] = sum_r seqE[b,s,r]*w[r] * hidE[b,h,r]
__global__ __launch_bounds__(256) void k3(const float* __restrict__ SeqE,
                                          const float* __restrict__ HidE,
                                          const float* __restrict__ cpw,
                                          float* __restrict__ out)
{
    __shared__ float s_w[32][36];
    __shared__ float s_h[64][36];
    const int tid = threadIdx.x;
    const int b  = blockIdx.z;
    const int s0 = blockIdx.x * 32;
    const int h0 = blockIdx.y * 64;

    {
        const int si = tid >> 3;
        const int r4 = (tid & 7) * 4;
        f32x4 v  = *(const f32x4*)(SeqE + ((size_t)(b * 1024 + s0 + si)) * 32 + r4);
        f32x4 wv = *(const f32x4*)(cpw + r4);
        v *= wv;
        *(f32x4*)&s_w[si][r4] = v;
    }
    #pragma unroll
    for (int t = 0; t < 2; ++t) {
        const int fi = tid + t * 256;
        const int hx = fi >> 3;
        const int r4 = (fi & 7) * 4;
        f32x4 v = *(const f32x4*)(HidE + ((size_t)(b * 1024 + h0 + hx)) * 32 + r4);
        *(f32x4*)&s_h[hx][r4] = v;
    }
    __syncthreads();

    const int hx = tid & 63;
    const int sg = tid >> 6;
    float hv[32];
    #pragma unroll
    for (int r4 = 0; r4 < 32; r4 += 4) {
        f32x4 v = *(const f32x4*)&s_h[hx][r4];
        hv[r4] = v.x; hv[r4+1] = v.y; hv[r4+2] = v.z; hv[r4+3] = v.w;
    }
    float res[8];
    #pragma unroll
    for (int si = 0; si < 8; ++si) {
        const int s = sg * 8 + si;
        float acc = 0.f;
        #pragma unroll
        for (int r4 = 0; r4 < 32; r4 += 4) {
            f32x4 v = *(const f32x4*)&s_w[s][r4];
            acc += v.x * hv[r4] + v.y * hv[r4+1] + v.z * hv[r4+2] + v.w * hv[r4+3];
        }
        res[si] = acc;
    }
    #pragma unroll
    for (int si = 0; si < 8; ++si) {
        const int s = s0 + sg * 8 + si;
        out[((size_t)(b * 1024 + s)) * 1024 + h0 + hx] = res[si];
    }
}

extern "C" void kernel_launch(void* const* d_in, const int* in_sizes, int n_in,
                              void* d_out, int out_size, void* d_ws, size_t ws_size,
                              hipStream_t stream) {
    const float* hs   = (const float*)d_in[0];
    // d_in[1] = all_indices: identically (n/H, n%H) -> computed implicitly
    const float* seqW = (const float*)d_in[2];
    const float* hidW = (const float*)d_in[3];
    const float* cpw  = (const float*)d_in[4];
    float* out = (float*)d_out;

    float* E = (float*)d_ws;                    // [2][4096][32] = 1 MB
    float* P = E + (size_t)2 * 4096 * 32;       // [4][4096][32] = 2 MB

    gemm_fused<<<512, 256, 0, stream>>>(hs, seqW, hidW, E, P);
    kreduce<<<128, 256, 0, stream>>>(P, E + (size_t)4096 * 32);
    dim3 grid3(32, 16, 4);
    k3<<<grid3, 256, 0, stream>>>(E, E + (size_t)4096 * 32, cpw, out);
}

// Round 8
// 25.545 us; speedup vs baseline: 1.2041x; 1.0850x over previous
//
#include <hip/hip_runtime.h>

typedef __attribute__((ext_vector_type(8))) short bf16x8;
typedef __attribute__((ext_vector_type(4))) float f32x4;
typedef __attribute__((ext_vector_type(2))) float f32x2;

// Native cast -> v_cvt_pk_bf16_f32 on gfx950 (RNE).
__device__ __forceinline__ short f2bf(float x) {
    union { __bf16 h; short s; } u;
    u.h = (__bf16)x;
    return u.s;
}

// K1: fused skinny GEMMs, 384 blocks x 256 thr (2 dispatches total this round).
//  bid<256 (seq, R4 verbatim): 16-row tile, 4 waves K-split-256, LDS reduce,
//    writes final seqE. A rows contiguous -> f32x4 direct loads.
//  bid>=256 (hid, CHANGED): 32-row tile (t=bid-256, m0=t*32), so the 16-lane
//    group's two row-subtiles (h0..h0+15, h0+16..h0+31) consume FULL 128B cache
//    lines within one k-step (R4's 16-row tiles used 64B of each line -> 2x
//    overfetch at strided-64B BW). 4 waves K-split-256, each wave computes 2
//    row-subtiles x 2 n-tiles = 4 accs; LDS reduce red[4][32][32]; final hidE.
// MFMA k-slot mapping kg(g,j)=8g+j identical for A and B -> k-permutation invariant.
__global__ __launch_bounds__(256) void gemm_fused(
    const float* __restrict__ hs, const float* __restrict__ seqW,
    const float* __restrict__ hidW, float* __restrict__ E /* [2][4096][32] */)
{
    __shared__ float lds[4096];   // seq: red[4][16][32]=2048; hid: red[4][32][32]=4096

    const int bid = blockIdx.x;
    const int tid = threadIdx.x;
    const int wv  = tid >> 6;
    const int l   = tid & 63;
    const int l15 = l & 15;
    const int g   = l >> 4;

    if (bid < 256) {
        // ---------------- seq path (R4 verbatim) ----------------
        const int m0 = bid * 16;
        const size_t arow = (size_t)(m0 + l15) << 10;
        f32x4 acc0 = {0.f,0.f,0.f,0.f}, acc1 = {0.f,0.f,0.f,0.f};
        const int kbase = wv * 256;

        for (int ks = 0; ks < 8; ++ks) {
            const int kb = kbase + ks * 32 + g * 8;
            bf16x8 af, bf0, bf1;
            {
                const f32x4* pa = (const f32x4*)(hs + arow + kb);
                f32x4 a0 = pa[0], a1 = pa[1];
                af[0]=f2bf(a0.x); af[1]=f2bf(a0.y); af[2]=f2bf(a0.z); af[3]=f2bf(a0.w);
                af[4]=f2bf(a1.x); af[5]=f2bf(a1.y); af[6]=f2bf(a1.z); af[7]=f2bf(a1.w);
            }
            {
                const f32x4* pb = (const f32x4*)(seqW + (size_t)l15 * 1024 + kb);
                f32x4 b0 = pb[0], b1 = pb[1];
                bf0[0]=f2bf(b0.x); bf0[1]=f2bf(b0.y); bf0[2]=f2bf(b0.z); bf0[3]=f2bf(b0.w);
                bf0[4]=f2bf(b1.x); bf0[5]=f2bf(b1.y); bf0[6]=f2bf(b1.z); bf0[7]=f2bf(b1.w);
            }
            {
                const f32x4* pb = (const f32x4*)(seqW + (size_t)(l15 + 16) * 1024 + kb);
                f32x4 b0 = pb[0], b1 = pb[1];
                bf1[0]=f2bf(b0.x); bf1[1]=f2bf(b0.y); bf1[2]=f2bf(b0.z); bf1[3]=f2bf(b0.w);
                bf1[4]=f2bf(b1.x); bf1[5]=f2bf(b1.y); bf1[6]=f2bf(b1.z); bf1[7]=f2bf(b1.w);
            }
            acc0 = __builtin_amdgcn_mfma_f32_16x16x32_bf16(af, bf0, acc0, 0, 0, 0);
            acc1 = __builtin_amdgcn_mfma_f32_16x16x32_bf16(af, bf1, acc1, 0, 0, 0);
        }
        // C/D layout (m89-verified): col = lane&15, row = (lane>>4)*4 + reg
        #pragma unroll
        for (int r = 0; r < 4; ++r) {
            lds[wv * 512 + (4 * g + r) * 32 + l15]      = acc0[r];
            lds[wv * 512 + (4 * g + r) * 32 + l15 + 16] = acc1[r];
        }
        __syncthreads();
        const int o = tid * 2;
        f32x2 v;
        v.x = lds[o]     + lds[512 + o]     + lds[1024 + o]     + lds[1536 + o];
        v.y = lds[o + 1] + lds[512 + o + 1] + lds[1024 + o + 1] + lds[1536 + o + 1];
        *(f32x2*)(E + (size_t)m0 * 32 + o) = v;
    } else {
        // ---------------- hid path: 32-row tiles, full-line loads ----------------
        const int t  = bid - 256;        // 0..127
        const int m0 = t * 32;           // row = b*1024 + h
        const int mr0 = m0 + l15;        // subtile 0 row
        const int mr1 = m0 + 16 + l15;   // subtile 1 row
        const size_t arow0 = ((size_t)(mr0 >> 10) << 20) + (size_t)(mr0 & 1023);
        const size_t arow1 = ((size_t)(mr1 >> 10) << 20) + (size_t)(mr1 & 1023);

        f32x4 acc00 = {0.f,0.f,0.f,0.f}, acc01 = {0.f,0.f,0.f,0.f};
        f32x4 acc10 = {0.f,0.f,0.f,0.f}, acc11 = {0.f,0.f,0.f,0.f};
        const int kbase = wv * 256;

        for (int ks = 0; ks < 8; ++ks) {
            const int kb = kbase + ks * 32 + g * 8;
            bf16x8 af0, af1, bf0, bf1;
            {
                const float* pa0 = hs + arow0 + (size_t)kb * 1024;
                const float* pa1 = hs + arow1 + (size_t)kb * 1024;
                float a0[8], a1[8];
                #pragma unroll
                for (int j = 0; j < 8; ++j) a0[j] = pa0[(size_t)j * 1024];
                #pragma unroll
                for (int j = 0; j < 8; ++j) a1[j] = pa1[(size_t)j * 1024];
                #pragma unroll
                for (int j = 0; j < 8; ++j) { af0[j] = f2bf(a0[j]); af1[j] = f2bf(a1[j]); }
            }
            {
                const f32x4* pb = (const f32x4*)(hidW + (size_t)l15 * 1024 + kb);
                f32x4 b0 = pb[0], b1 = pb[1];
                bf0[0]=f2bf(b0.x); bf0[1]=f2bf(b0.y); bf0[2]=f2bf(b0.z); bf0[3]=f2bf(b0.w);
                bf0[4]=f2bf(b1.x); bf0[5]=f2bf(b1.y); bf0[6]=f2bf(b1.z); bf0[7]=f2bf(b1.w);
            }
            {
                const f32x4* pb = (const f32x4*)(hidW + (size_t)(l15 + 16) * 1024 + kb);
                f32x4 b0 = pb[0], b1 = pb[1];
                bf1[0]=f2bf(b0.x); bf1[1]=f2bf(b0.y); bf1[2]=f2bf(b0.z); bf1[3]=f2bf(b0.w);
                bf1[4]=f2bf(b1.x); bf1[5]=f2bf(b1.y); bf1[6]=f2bf(b1.z); bf1[7]=f2bf(b1.w);
            }
            acc00 = __builtin_amdgcn_mfma_f32_16x16x32_bf16(af0, bf0, acc00, 0, 0, 0);
            acc01 = __builtin_amdgcn_mfma_f32_16x16x32_bf16(af0, bf1, acc01, 0, 0, 0);
            acc10 = __builtin_amdgcn_mfma_f32_16x16x32_bf16(af1, bf0, acc10, 0, 0, 0);
            acc11 = __builtin_amdgcn_mfma_f32_16x16x32_bf16(af1, bf1, acc11, 0, 0, 0);
        }

        // red[wv][32][32]: rows 0..15 subtile0, 16..31 subtile1; cols = r-dim.
        #pragma unroll
        for (int r = 0; r < 4; ++r) {
            lds[wv * 1024 + (4 * g + r) * 32 + l15]           = acc00[r];
            lds[wv * 1024 + (4 * g + r) * 32 + l15 + 16]      = acc01[r];
            lds[wv * 1024 + (16 + 4 * g + r) * 32 + l15]      = acc10[r];
            lds[wv * 1024 + (16 + 4 * g + r) * 32 + l15 + 16] = acc11[r];
        }
        __syncthreads();
        // Sum 4 K-slice partials; each thread emits 4 consecutive floats (f32x4).
        const int o = tid * 4;
        f32x4 v = *(const f32x4*)&lds[o]
                + *(const f32x4*)&lds[1024 + o]
                + *(const f32x4*)&lds[2048 + o]
                + *(const f32x4*)&lds[3072 + o];
        *(f32x4*)(E + (size_t)4096 * 32 + (size_t)m0 * 32 + o) = v;
    }
}

// K3: verbatim R4. out[b][s][h] = sum_r seqE[b,s,r]*w[r] * hidE[b,h,r]
__global__ __launch_bounds__(256) void k3(const float* __restrict__ SeqE,
                                          const float* __restrict__ HidE,
                                          const float* __restrict__ cpw,
                                          float* __restrict__ out)
{
    __shared__ float s_w[32][36];   // seq tile, pre-weighted
    __shared__ float s_h[64][36];   // hid tile
    const int tid = threadIdx.x;
    const int b  = blockIdx.z;
    const int s0 = blockIdx.x * 32;
    const int h0 = blockIdx.y * 64;

    {
        const int si = tid >> 3;
        const int r4 = (tid & 7) * 4;
        f32x4 v  = *(const f32x4*)(SeqE + ((size_t)(b * 1024 + s0 + si)) * 32 + r4);
        f32x4 wv = *(const f32x4*)(cpw + r4);
        v *= wv;
        *(f32x4*)&s_w[si][r4] = v;
    }
    #pragma unroll
    for (int t = 0; t < 2; ++t) {
        const int fi = tid + t * 256;
        const int hx = fi >> 3;
        const int r4 = (fi & 7) * 4;
        f32x4 v = *(const f32x4*)(HidE + ((size_t)(b * 1024 + h0 + hx)) * 32 + r4);
        *(f32x4*)&s_h[hx][r4] = v;
    }
    __syncthreads();

    const int hx = tid & 63;
    const int sg = tid >> 6;
    float hv[32];
    #pragma unroll
    for (int r4 = 0; r4 < 32; r4 += 4) {
        f32x4 v = *(const f32x4*)&s_h[hx][r4];
        hv[r4] = v.x; hv[r4+1] = v.y; hv[r4+2] = v.z; hv[r4+3] = v.w;
    }
    float res[8];
    #pragma unroll
    for (int si = 0; si < 8; ++si) {
        const int s = sg * 8 + si;
        float acc = 0.f;
        #pragma unroll
        for (int r4 = 0; r4 < 32; r4 += 4) {
            f32x4 v = *(const f32x4*)&s_w[s][r4];   // wave-uniform broadcast
            acc += v.x * hv[r4] + v.y * hv[r4+1] + v.z * hv[r4+2] + v.w * hv[r4+3];
        }
        res[si] = acc;
    }
    #pragma unroll
    for (int si = 0; si < 8; ++si) {
        const int s = s0 + sg * 8 + si;
        out[((size_t)(b * 1024 + s)) * 1024 + h0 + hx] = res[si];
    }
}

extern "C" void kernel_launch(void* const* d_in, const int* in_sizes, int n_in,
                              void* d_out, int out_size, void* d_ws, size_t ws_size,
                              hipStream_t stream) {
    const float* hs   = (const float*)d_in[0];
    // d_in[1] = all_indices: identically (n/H, n%H) -> computed implicitly
    const float* seqW = (const float*)d_in[2];
    const float* hidW = (const float*)d_in[3];
    const float* cpw  = (const float*)d_in[4];
    float* out = (float*)d_out;

    float* E = (float*)d_ws;              // [2][4096][32] fp32, 1 MB

    gemm_fused<<<384, 256, 0, stream>>>(hs, seqW, hidW, E);
    dim3 grid3(32, 16, 4);
    k3<<<grid3, 256, 0, stream>>>(E, E + (size_t)4096 * 32, cpw, out);
}

// Round 9
// 22.576 us; speedup vs baseline: 1.3625x; 1.1315x over previous
//
#include <hip/hip_runtime.h>

typedef __attribute__((ext_vector_type(8))) short bf16x8;
typedef __attribute__((ext_vector_type(4))) float f32x4;
typedef __attribute__((ext_vector_type(2))) float f32x2;

// Native cast -> v_cvt_pk_bf16_f32 on gfx950 (RNE).
__device__ __forceinline__ unsigned short f2bf(float x) {
    union { __bf16 h; unsigned short s; } u;
    u.h = (__bf16)x;
    return u.s;
}

// K1: fused skinny GEMMs (R4 structure verbatim), epilogue now emits BF16
// embeddings E16[2][4096][32] with cp_weight folded into the seq half.
//   blocks 0..255  : seqE tile m0=bid*16 (A rows contiguous, f32x4 loads)
//   blocks 256..511: hidE tile (A strided 4KB scalar loads)
// 4 waves K-split-256 -> LDS fp32 reduce -> cvt+pack -> 4B store per thread.
// MFMA k-slot mapping kg(g,j)=8g+j identical for A and B -> k-permutation invariant.
__global__ __launch_bounds__(256) void gemm_fused(
    const float* __restrict__ hs, const float* __restrict__ seqW,
    const float* __restrict__ hidW, const float* __restrict__ cpw,
    unsigned short* __restrict__ E16 /* [2][4096][32] bf16 */)
{
    __shared__ float red[4][16][32];

    const int bid = blockIdx.x;
    const bool hid = bid >= 256;
    const int mt  = hid ? bid - 256 : bid;
    const int tid = threadIdx.x;
    const int wv  = tid >> 6;
    const int l   = tid & 63;
    const int l15 = l & 15;
    const int g   = l >> 4;
    const int m0  = mt * 16;
    const int mrow = m0 + l15;

    const float* __restrict__ W = hid ? hidW : seqW;
    size_t arow;
    if (hid) arow = ((size_t)(mrow >> 10) << 20) + (size_t)(mrow & 1023);
    else     arow = (size_t)mrow << 10;

    f32x4 acc0 = {0.f,0.f,0.f,0.f}, acc1 = {0.f,0.f,0.f,0.f};
    const int kbase = wv * 256;

    for (int ks = 0; ks < 8; ++ks) {
        const int kb = kbase + ks * 32 + g * 8;
        bf16x8 af, bf0, bf1;
        if (hid) {
            const float* pa = hs + arow + (size_t)kb * 1024;
            float a[8];
            #pragma unroll
            for (int j = 0; j < 8; ++j) a[j] = pa[(size_t)j * 1024];
            #pragma unroll
            for (int j = 0; j < 8; ++j) af[j] = (short)f2bf(a[j]);
        } else {
            const f32x4* pa = (const f32x4*)(hs + arow + kb);
            f32x4 a0 = pa[0], a1 = pa[1];
            af[0]=(short)f2bf(a0.x); af[1]=(short)f2bf(a0.y); af[2]=(short)f2bf(a0.z); af[3]=(short)f2bf(a0.w);
            af[4]=(short)f2bf(a1.x); af[5]=(short)f2bf(a1.y); af[6]=(short)f2bf(a1.z); af[7]=(short)f2bf(a1.w);
        }
        {
            const f32x4* pb = (const f32x4*)(W + (size_t)l15 * 1024 + kb);
            f32x4 b0 = pb[0], b1 = pb[1];
            bf0[0]=(short)f2bf(b0.x); bf0[1]=(short)f2bf(b0.y); bf0[2]=(short)f2bf(b0.z); bf0[3]=(short)f2bf(b0.w);
            bf0[4]=(short)f2bf(b1.x); bf0[5]=(short)f2bf(b1.y); bf0[6]=(short)f2bf(b1.z); bf0[7]=(short)f2bf(b1.w);
        }
        {
            const f32x4* pb = (const f32x4*)(W + (size_t)(l15 + 16) * 1024 + kb);
            f32x4 b0 = pb[0], b1 = pb[1];
            bf1[0]=(short)f2bf(b0.x); bf1[1]=(short)f2bf(b0.y); bf1[2]=(short)f2bf(b0.z); bf1[3]=(short)f2bf(b0.w);
            bf1[4]=(short)f2bf(b1.x); bf1[5]=(short)f2bf(b1.y); bf1[6]=(short)f2bf(b1.z); bf1[7]=(short)f2bf(b1.w);
        }
        acc0 = __builtin_amdgcn_mfma_f32_16x16x32_bf16(af, bf0, acc0, 0, 0, 0);
        acc1 = __builtin_amdgcn_mfma_f32_16x16x32_bf16(af, bf1, acc1, 0, 0, 0);
    }

    // C/D layout (m89-verified): col = lane&15, row = (lane>>4)*4 + reg
    #pragma unroll
    for (int r = 0; r < 4; ++r) {
        red[wv][4 * g + r][l15]      = acc0[r];
        red[wv][4 * g + r][l15 + 16] = acc1[r];
    }
    __syncthreads();

    // Sum 4 wave-partials -> fold cpw (seq only) -> bf16 pack -> 4B store.
    const int o = tid * 2;
    const float* rf = &red[0][0][0];
    float vx = rf[o]     + rf[512 + o]     + rf[1024 + o]     + rf[1536 + o];
    float vy = rf[o + 1] + rf[512 + o + 1] + rf[1024 + o + 1] + rf[1536 + o + 1];
    if (!hid) {
        f32x2 w = *(const f32x2*)(cpw + (o & 31));
        vx *= w.x; vy *= w.y;
    }
    unsigned pk = (unsigned)f2bf(vx) | ((unsigned)f2bf(vy) << 16);
    unsigned short* Eo = E16 + (hid ? (size_t)4096 * 32 : 0) + (size_t)m0 * 32 + o;
    *(unsigned*)Eo = pk;
}

// K3: rank-32 GEMM via MFMA, zero LDS.
//   out[b][s][h] = sum_r seqE16[b*1024+s][r] * hidE16[b*1024+h][r]  (cpw folded)
// K=32 = one 16x16x32 MFMA per output tile. Block 256 thr = 4 waves; wave =
// 32s x 64h (2 A-frags, 4 B-frags, 8 MFMAs, 32 dword stores). Block = 128s x 64h.
// grid (16 h-tiles, 8 s-tiles, 4 b) = 512 blocks. Same kg(g,j)=8g+j on both
// operands; D layout col=lane&15 (h), row=(lane>>4)*4+reg (s).
__global__ __launch_bounds__(256) void k3(const unsigned short* __restrict__ E16,
                                          float* __restrict__ out)
{
    const int tid = threadIdx.x;
    const int wv  = tid >> 6;
    const int l   = tid & 63;
    const int l15 = l & 15;
    const int g   = l >> 4;
    const int b   = blockIdx.z;
    const int s0  = blockIdx.y * 128 + wv * 32;
    const int h0  = blockIdx.x * 64;

    const unsigned short* As = E16 + ((size_t)(b * 1024 + s0)) * 32;
    const unsigned short* Bh = E16 + (size_t)4096 * 32 + ((size_t)(b * 1024 + h0)) * 32;

    bf16x8 af[2], bfr[4];
    #pragma unroll
    for (int i = 0; i < 2; ++i)
        af[i] = *(const bf16x8*)(As + (size_t)(i * 16 + l15) * 32 + g * 8);
    #pragma unroll
    for (int j = 0; j < 4; ++j)
        bfr[j] = *(const bf16x8*)(Bh + (size_t)(j * 16 + l15) * 32 + g * 8);

    const f32x4 zero = {0.f, 0.f, 0.f, 0.f};
    f32x4 acc[2][4];
    #pragma unroll
    for (int i = 0; i < 2; ++i)
        #pragma unroll
        for (int j = 0; j < 4; ++j)
            acc[i][j] = __builtin_amdgcn_mfma_f32_16x16x32_bf16(af[i], bfr[j], zero, 0, 0, 0);

    #pragma unroll
    for (int i = 0; i < 2; ++i)
        #pragma unroll
        for (int r = 0; r < 4; ++r) {
            float* orow = out + ((size_t)(b * 1024 + s0 + i * 16 + 4 * g + r)) * 1024 + h0;
            #pragma unroll
            for (int j = 0; j < 4; ++j)
                orow[j * 16 + l15] = acc[i][j][r];
        }
}

extern "C" void kernel_launch(void* const* d_in, const int* in_sizes, int n_in,
                              void* d_out, int out_size, void* d_ws, size_t ws_size,
                              hipStream_t stream) {
    const float* hs   = (const float*)d_in[0];
    // d_in[1] = all_indices: identically (n/H, n%H) -> computed implicitly
    const float* seqW = (const float*)d_in[2];
    const float* hidW = (const float*)d_in[3];
    const float* cpw  = (const float*)d_in[4];
    float* out = (float*)d_out;

    unsigned short* E16 = (unsigned short*)d_ws;   // [2][4096][32] bf16, 512 KB

    gemm_fused<<<512, 256, 0, stream>>>(hs, seqW, hidW, cpw, E16);
    dim3 grid3(16, 8, 4);
    k3<<<grid3, 256, 0, stream>>>(E16, out);
}